// Round 3
// baseline (446.477 us; speedup 1.0000x reference)
//
#include <hip/hip_runtime.h>

typedef __bf16  bf16x8 __attribute__((ext_vector_type(8)));
typedef float   f32x16 __attribute__((ext_vector_type(16)));
typedef unsigned short u16x8 __attribute__((ext_vector_type(8)));

#define NP    31744   /* padded n: 32 b * 31 p * 32 q  (q=31 is a dead pad lane) */
#define NROWS 992     /* 32 b * 31 p */

__device__ __forceinline__ unsigned short f2bf(float f) {
    union { float f; unsigned int u; } v; v.f = f;
    unsigned int r = (v.u + 0x7fffu + ((v.u >> 16) & 1u)) >> 16;
    return (unsigned short)r;
}

__device__ __forceinline__ void async16(const void* g, void* l) {
    __builtin_amdgcn_global_load_lds(
        (const __attribute__((address_space(1))) void*)g,
        (__attribute__((address_space(3))) void*)l, 16, 0, 0);
}

// ---------------------------------------------------------------------------
// Kernel A: weight transform U = G g G^T, stored bf16 in MFMA B-fragment order:
//   Up[((ad*16 + cg)*256 + k)*8 + j]   where c = cg*8 + j
// ---------------------------------------------------------------------------
__global__ void wino_wtrans(const float* __restrict__ w, unsigned short* __restrict__ Up) {
    int k = blockIdx.x;        // 0..255
    int c = threadIdx.x;       // 0..127
    const float* g = w + (k * 128 + c) * 9;
    float g00=g[0],g01=g[1],g02=g[2],g10=g[3],g11=g[4],g12=g[5],g20=g[6],g21=g[7],g22=g[8];
    float T[4][3];
    T[0][0]=g00;                    T[0][1]=g01;                    T[0][2]=g02;
    T[1][0]=0.5f*(g00+g10+g20);     T[1][1]=0.5f*(g01+g11+g21);     T[1][2]=0.5f*(g02+g12+g22);
    T[2][0]=0.5f*(g00-g10+g20);     T[2][1]=0.5f*(g01-g11+g21);     T[2][2]=0.5f*(g02-g12+g22);
    T[3][0]=g20;                    T[3][1]=g21;                    T[3][2]=g22;
    int cg = c >> 3, j = c & 7;
    #pragma unroll
    for (int a = 0; a < 4; ++a) {
        float u0 = T[a][0];
        float u1 = 0.5f*(T[a][0]+T[a][1]+T[a][2]);
        float u2 = 0.5f*(T[a][0]-T[a][1]+T[a][2]);
        float u3 = T[a][2];
        float uu[4] = {u0,u1,u2,u3};
        #pragma unroll
        for (int d = 0; d < 4; ++d) {
            Up[(((size_t)((a*4+d)*16 + cg))*256 + k)*8 + j] = f2bf(uu[d]);
        }
    }
}

// ---------------------------------------------------------------------------
// Kernel B: input transform. Grid is (cg, nb) so consecutive blocks share the
// same 4 x-rows (different c-slice) -> x streams from HBM once, not 16 times.
// ---------------------------------------------------------------------------
#define XS_STRIDE 66   /* 64 + 2 pad: breaks the stride-64 bank collision */
__global__ __launch_bounds__(256) void wino_itrans(const float* __restrict__ x,
                                                   unsigned short* __restrict__ Vp) {
    __shared__ float          xs[8 * 4 * XS_STRIDE];       // 8448 B
    __shared__ unsigned short vs[16][32][8];               // 8192 B

    int t  = threadIdx.x;
    int cg = blockIdx.x;       // 0..15
    int nb = blockIdx.y;       // 0..991  (= b*31 + p)
    int b  = nb / 31, p = nb - b * 31;

    // ---- stage x: 2048 floats, each thread 2 contiguous float4 (32B) ----
    {
        const float* xbase = x + (((size_t)b * 128 + cg * 8) * 64 + 2 * p) * 64;
        int f = t * 2;                       // float4 index 0..511
        int cl  = f >> 6;                    // c_local 0..7   (64 float4 per c)
        int rem = f & 63;
        int rw  = rem >> 4;                  // row 0..3       (16 float4 per row)
        int c4  = rem & 15;                  // float4 col
        float4 v0 = *(const float4*)(xbase + ((size_t)cl * 64 + rw) * 64 + c4 * 4);
        float4 v1 = *(const float4*)(xbase + ((size_t)cl * 64 + rw) * 64 + c4 * 4 + 4);
        float* dst = xs + (cl * 4 + rw) * XS_STRIDE + c4 * 4;
        dst[0]=v0.x; dst[1]=v0.y; dst[2]=v0.z; dst[3]=v0.w;
        dst[4]=v1.x; dst[5]=v1.y; dst[6]=v1.z; dst[7]=v1.w;
    }
    __syncthreads();

    // ---- compute V = Bt d Bt^T for (c_local=j, q) ----
    {
        int j = t & 7;
        int q = t >> 3;          // 0..31, q==31 is the pad lane
        float V[4][4];
        if (q >= 31) {
            #pragma unroll
            for (int a = 0; a < 4; ++a)
                #pragma unroll
                for (int d = 0; d < 4; ++d) V[a][d] = 0.f;
        } else {
            float dd[4][4];
            #pragma unroll
            for (int i = 0; i < 4; ++i) {
                const float* r = xs + (j * 4 + i) * XS_STRIDE + 2 * q;
                float2 u0 = *(const float2*)(r);
                float2 u1 = *(const float2*)(r + 2);
                dd[i][0]=u0.x; dd[i][1]=u0.y; dd[i][2]=u1.x; dd[i][3]=u1.y;
            }
            float s[4][4];
            #pragma unroll
            for (int jj = 0; jj < 4; ++jj) {
                s[0][jj] = dd[0][jj] - dd[2][jj];
                s[1][jj] = dd[1][jj] + dd[2][jj];
                s[2][jj] = dd[2][jj] - dd[1][jj];
                s[3][jj] = dd[1][jj] - dd[3][jj];
            }
            #pragma unroll
            for (int a = 0; a < 4; ++a) {
                V[a][0] = s[a][0] - s[a][2];
                V[a][1] = s[a][1] + s[a][2];
                V[a][2] = s[a][2] - s[a][1];
                V[a][3] = s[a][1] - s[a][3];
            }
        }
        #pragma unroll
        for (int a = 0; a < 4; ++a)
            #pragma unroll
            for (int d = 0; d < 4; ++d)
                vs[a * 4 + d][q][j] = f2bf(V[a][d]);
    }
    __syncthreads();

    // ---- write out: thread t -> (ad = t>>4), nl = t&15 and 16+(t&15) ----
    {
        int ad  = t >> 4;
        int nlo = t & 15;
        size_t base = ((size_t)(ad * 16 + cg) * NP + (size_t)nb * 32) * 8;
        u16x8 a0 = *(const u16x8*)&vs[ad][nlo][0];
        u16x8 a1 = *(const u16x8*)&vs[ad][nlo + 16][0];
        *(u16x8*)(Vp + base + nlo * 8)        = a0;
        *(u16x8*)(Vp + base + (nlo + 16) * 8) = a1;
    }
}

// ---------------------------------------------------------------------------
// Kernel C v3: LDS-tiled GEMM. Block = 128n x 128k, 8 waves (4n x 2k), wave
// tile = 32n x 64k. Per-ad V/U slices (32KB each) staged to LDS with
// global_load_lds width=16, double-buffered; fragments via ds_read_b128.
// 16 ad-GEMMs folded into 4 Y accumulators per 32x32 tile (At is 0/+-1).
// LDS reads: 1.5KB/MFMA vs 2KB/MFMA through L1 before, and LDS BW ~2x L1.
// ---------------------------------------------------------------------------
__global__ __launch_bounds__(512, 2) void wino_gemm(
        const unsigned short* __restrict__ Vp, const unsigned short* __restrict__ Up,
        const float* __restrict__ bias, float* __restrict__ out)
{
    // per buffer: V 16384 u16 (32KB) then U 16384 u16 (32KB). 2 buffers = 128KB.
    __shared__ unsigned short lds[2][32768];

    int t    = threadIdx.x;
    int lane = t & 63;
    int wave = t >> 6;                        // 0..7
    int l31  = lane & 31, q2 = lane >> 5;
    int wn   = wave & 3;                      // n sub-tile 0..3
    int wk   = wave >> 2;                     // k sub-tile 0..1
    int n0   = blockIdx.x * 128;
    int k0   = blockIdx.y * 128;

    f32x16 Y[2][4];
    #pragma unroll
    for (int kt = 0; kt < 2; ++kt)
        #pragma unroll
        for (int y = 0; y < 4; ++y)
            #pragma unroll
            for (int z = 0; z < 16; ++z) Y[kt][y][z] = 0.f;

    // ---- stage slice for ad into lds[buf]: 64 chunks of 1KB, 8 per wave ----
    auto stage = [&](int ad, int buf) {
        unsigned short* vdst = &lds[buf][0];
        unsigned short* udst = &lds[buf][16384];
        #pragma unroll
        for (int i = 0; i < 8; ++i) {
            int chunk = wave * 8 + i;         // 0..63 (wave-uniform)
            int isU   = chunk >> 5;
            int c5    = chunk & 31;
            int cg    = c5 >> 1, h = c5 & 1;
            if (!isU) {
                const unsigned short* g =
                    Vp + ((size_t)(ad * 16 + cg) * NP + n0 + h * 64 + lane) * 8;
                async16(g, vdst + (cg * 128 + h * 64) * 8);
            } else {
                const unsigned short* g =
                    Up + ((size_t)(ad * 16 + cg) * 256 + k0 + h * 64 + lane) * 8;
                async16(g, udst + (cg * 128 + h * 64) * 8);
            }
        }
    };

    stage(0, 0);

    #pragma unroll
    for (int ad = 0; ad < 16; ++ad) {
        __syncthreads();                      // drains stage(ad); WAR guard for stage(ad+1)
        if (ad < 15) stage(ad + 1, (ad + 1) & 1);

        const unsigned short* vb = &lds[ad & 1][0];
        const unsigned short* ub = &lds[ad & 1][16384];

        f32x16 m0, m1;
        #pragma unroll
        for (int z = 0; z < 16; ++z) { m0[z] = 0.f; m1[z] = 0.f; }

        #pragma unroll
        for (int cb = 0; cb < 8; ++cb) {
            int cg = cb * 2 + q2;
            bf16x8 av = *(const bf16x8*)&vb[(cg * 128 + wn * 32 + l31) * 8];
            bf16x8 b0 = *(const bf16x8*)&ub[(cg * 128 + wk * 64 + l31) * 8];
            bf16x8 b1 = *(const bf16x8*)&ub[(cg * 128 + wk * 64 + 32 + l31) * 8];
            m0 = __builtin_amdgcn_mfma_f32_32x32x16_bf16(av, b0, m0, 0, 0, 0);
            m1 = __builtin_amdgcn_mfma_f32_32x32x16_bf16(av, b1, m1, 0, 0, 0);
        }

        const int a_i = ad >> 2, d_i = ad & 3;
        constexpr float A0[4] = {1.f, 1.f,  1.f,  0.f};
        constexpr float A1[4] = {0.f, 1.f, -1.f, -1.f};
        const float w00 = A0[a_i]*A0[d_i], w01 = A0[a_i]*A1[d_i];
        const float w10 = A1[a_i]*A0[d_i], w11 = A1[a_i]*A1[d_i];
        if (w00 != 0.f) { Y[0][0] += w00 * m0; Y[1][0] += w00 * m1; }
        if (w01 != 0.f) { Y[0][1] += w01 * m0; Y[1][1] += w01 * m1; }
        if (w10 != 0.f) { Y[0][2] += w10 * m0; Y[1][2] += w10 * m1; }
        if (w11 != 0.f) { Y[0][3] += w11 * m0; Y[1][3] += w11 * m1; }
    }

    // ---- epilogue: lane owns k-plane; C/D row r -> q = (r&3)+8*(r>>2)+4*q2 ----
    int row = blockIdx.x * 4 + wn;            // 0..991 = b*31 + p
    int b = row / 31, p = row - (row / 31) * 31;
    #pragma unroll
    for (int kt = 0; kt < 2; ++kt) {
        int k = k0 + wk * 64 + kt * 32 + l31;
        float bv = bias[k];
        float* op = out + (size_t)(b * 256 + k) * 62 * 62;
        #pragma unroll
        for (int r = 0; r < 16; ++r) {
            int q = (r & 3) + 8 * (r >> 2) + 4 * q2;
            if (q < 31) {
                float2 v0 = make_float2(Y[kt][0][r] + bv, Y[kt][1][r] + bv);
                float2 v1 = make_float2(Y[kt][2][r] + bv, Y[kt][3][r] + bv);
                *(float2*)(op + (2 * p + 0) * 62 + 2 * q) = v0;
                *(float2*)(op + (2 * p + 1) * 62 + 2 * q) = v1;
            }
        }
    }
}

// ---------------------------------------------------------------------------
extern "C" void kernel_launch(void* const* d_in, const int* in_sizes, int n_in,
                              void* d_out, int out_size, void* d_ws, size_t ws_size,
                              hipStream_t stream) {
    const float* x    = (const float*)d_in[0];
    const float* w    = (const float*)d_in[1];
    const float* bias = (const float*)d_in[2];
    float* out = (float*)d_out;

    unsigned short* Up = (unsigned short*)d_ws;        // 16*16*256*8 = 524288 bf16 = 1 MB
    unsigned short* Vp = Up + 524288;                  // 16*16*NP*8 bf16 = ~130 MB

    wino_wtrans<<<dim3(256),        dim3(128), 0, stream>>>(w, Up);
    wino_itrans<<<dim3(16, NROWS),  dim3(256), 0, stream>>>(x, Vp);
    wino_gemm  <<<dim3(248, 2),     dim3(512), 0, stream>>>(Vp, Up, bias, out);
}

// Round 4
// 388.595 us; speedup vs baseline: 1.1490x; 1.1490x over previous
//
#include <hip/hip_runtime.h>

typedef __bf16  bf16x8 __attribute__((ext_vector_type(8)));
typedef float   f32x16 __attribute__((ext_vector_type(16)));
typedef unsigned short u16x8 __attribute__((ext_vector_type(8)));

#define NP    31744   /* padded n: 32 b * 31 p * 32 q  (q=31 is a dead pad lane) */
#define NROWS 992     /* 32 b * 31 p */

__device__ __forceinline__ unsigned short f2bf(float f) {
    union { float f; unsigned int u; } v; v.f = f;
    unsigned int r = (v.u + 0x7fffu + ((v.u >> 16) & 1u)) >> 16;
    return (unsigned short)r;
}

__device__ __forceinline__ void async16(const void* g, void* l) {
    __builtin_amdgcn_global_load_lds(
        (const __attribute__((address_space(1))) void*)g,
        (__attribute__((address_space(3))) void*)l, 16, 0, 0);
}

// ---------------------------------------------------------------------------
// Kernel A: weight transform U = G g G^T, stored bf16 in MFMA B-fragment order:
//   Up[((ad*16 + cg)*256 + k)*8 + j]   where c = cg*8 + j
// ---------------------------------------------------------------------------
__global__ void wino_wtrans(const float* __restrict__ w, unsigned short* __restrict__ Up) {
    int k = blockIdx.x;        // 0..255
    int c = threadIdx.x;       // 0..127
    const float* g = w + (k * 128 + c) * 9;
    float g00=g[0],g01=g[1],g02=g[2],g10=g[3],g11=g[4],g12=g[5],g20=g[6],g21=g[7],g22=g[8];
    float T[4][3];
    T[0][0]=g00;                    T[0][1]=g01;                    T[0][2]=g02;
    T[1][0]=0.5f*(g00+g10+g20);     T[1][1]=0.5f*(g01+g11+g21);     T[1][2]=0.5f*(g02+g12+g22);
    T[2][0]=0.5f*(g00-g10+g20);     T[2][1]=0.5f*(g01-g11+g21);     T[2][2]=0.5f*(g02-g12+g22);
    T[3][0]=g20;                    T[3][1]=g21;                    T[3][2]=g22;
    int cg = c >> 3, j = c & 7;
    #pragma unroll
    for (int a = 0; a < 4; ++a) {
        float u0 = T[a][0];
        float u1 = 0.5f*(T[a][0]+T[a][1]+T[a][2]);
        float u2 = 0.5f*(T[a][0]-T[a][1]+T[a][2]);
        float u3 = T[a][2];
        float uu[4] = {u0,u1,u2,u3};
        #pragma unroll
        for (int d = 0; d < 4; ++d) {
            Up[(((size_t)((a*4+d)*16 + cg))*256 + k)*8 + j] = f2bf(uu[d]);
        }
    }
}

// ---------------------------------------------------------------------------
// Kernel B (unchanged from round 3 for attribution): input transform.
// ---------------------------------------------------------------------------
#define XS_STRIDE 66   /* 64 + 2 pad: breaks the stride-64 bank collision */
__global__ __launch_bounds__(256) void wino_itrans(const float* __restrict__ x,
                                                   unsigned short* __restrict__ Vp) {
    __shared__ float          xs[8 * 4 * XS_STRIDE];       // 8448 B
    __shared__ unsigned short vs[16][32][8];               // 8192 B

    int t  = threadIdx.x;
    int cg = blockIdx.x;       // 0..15
    int nb = blockIdx.y;       // 0..991  (= b*31 + p)
    int b  = nb / 31, p = nb - b * 31;

    // ---- stage x: 2048 floats, each thread 2 contiguous float4 (32B) ----
    {
        const float* xbase = x + (((size_t)b * 128 + cg * 8) * 64 + 2 * p) * 64;
        int f = t * 2;                       // float4 index 0..511
        int cl  = f >> 6;                    // c_local 0..7   (64 float4 per c)
        int rem = f & 63;
        int rw  = rem >> 4;                  // row 0..3       (16 float4 per row)
        int c4  = rem & 15;                  // float4 col
        float4 v0 = *(const float4*)(xbase + ((size_t)cl * 64 + rw) * 64 + c4 * 4);
        float4 v1 = *(const float4*)(xbase + ((size_t)cl * 64 + rw) * 64 + c4 * 4 + 4);
        float* dst = xs + (cl * 4 + rw) * XS_STRIDE + c4 * 4;
        dst[0]=v0.x; dst[1]=v0.y; dst[2]=v0.z; dst[3]=v0.w;
        dst[4]=v1.x; dst[5]=v1.y; dst[6]=v1.z; dst[7]=v1.w;
    }
    __syncthreads();

    // ---- compute V = Bt d Bt^T for (c_local=j, q) ----
    {
        int j = t & 7;
        int q = t >> 3;          // 0..31, q==31 is the pad lane
        float V[4][4];
        if (q >= 31) {
            #pragma unroll
            for (int a = 0; a < 4; ++a)
                #pragma unroll
                for (int d = 0; d < 4; ++d) V[a][d] = 0.f;
        } else {
            float dd[4][4];
            #pragma unroll
            for (int i = 0; i < 4; ++i) {
                const float* r = xs + (j * 4 + i) * XS_STRIDE + 2 * q;
                float2 u0 = *(const float2*)(r);
                float2 u1 = *(const float2*)(r + 2);
                dd[i][0]=u0.x; dd[i][1]=u0.y; dd[i][2]=u1.x; dd[i][3]=u1.y;
            }
            float s[4][4];
            #pragma unroll
            for (int jj = 0; jj < 4; ++jj) {
                s[0][jj] = dd[0][jj] - dd[2][jj];
                s[1][jj] = dd[1][jj] + dd[2][jj];
                s[2][jj] = dd[2][jj] - dd[1][jj];
                s[3][jj] = dd[1][jj] - dd[3][jj];
            }
            #pragma unroll
            for (int a = 0; a < 4; ++a) {
                V[a][0] = s[a][0] - s[a][2];
                V[a][1] = s[a][1] + s[a][2];
                V[a][2] = s[a][2] - s[a][1];
                V[a][3] = s[a][1] - s[a][3];
            }
        }
        #pragma unroll
        for (int a = 0; a < 4; ++a)
            #pragma unroll
            for (int d = 0; d < 4; ++d)
                vs[a * 4 + d][q][j] = f2bf(V[a][d]);
    }
    __syncthreads();

    // ---- write out: thread t -> (ad = t>>4), nl = t&15 and 16+(t&15) ----
    {
        int ad  = t >> 4;
        int nlo = t & 15;
        size_t base = ((size_t)(ad * 16 + cg) * NP + (size_t)nb * 32) * 8;
        u16x8 a0 = *(const u16x8*)&vs[ad][nlo][0];
        u16x8 a1 = *(const u16x8*)&vs[ad][nlo + 16][0];
        *(u16x8*)(Vp + base + nlo * 8)        = a0;
        *(u16x8*)(Vp + base + (nlo + 16) * 8) = a1;
    }
}

// ---------------------------------------------------------------------------
// Kernel C v4: m97-template GEMM over combined reduction R = 2048 (ad major,
// c minor). Block = 64n x 128k, 4 waves (2n x 2k), wave tile 32n x 64k.
// BK = 64 -> 32 steps; step s has ad = s>>1 (compile-time via full unroll).
// Single 24KB LDS buffer, 2-barrier loop, global_load_lds width-16 staging.
// m accumulates over the 2 steps of one ad, then folds into Y (At = 0/+-1,
// constant-folded to adds). k-sibling blocks adjacent for L2/L3 reuse of Vp.
// ---------------------------------------------------------------------------
__global__ __launch_bounds__(256) void wino_gemm(
        const unsigned short* __restrict__ Vp, const unsigned short* __restrict__ Up,
        const float* __restrict__ bias, float* __restrict__ out)
{
    __shared__ __align__(16) unsigned short As[8 * 64 * 8];    //  8 KB [h][nl][j]
    __shared__ __align__(16) unsigned short Bs[8 * 128 * 8];   // 16 KB [h][kl][j]

    int t    = threadIdx.x;
    int lane = t & 63;
    int wave = t >> 6;                        // 0..3
    int l31  = lane & 31, q2 = lane >> 5;
    int wn   = wave & 1,  wk = wave >> 1;
    int bid  = blockIdx.x;
    int nb   = bid >> 1;                      // 0..495  (64-n slice)
    int kb   = bid & 1;                       // sibling k-blocks adjacent
    int n0   = nb * 64;
    int k0   = kb * 128;

    f32x16 Y[2][4];
    #pragma unroll
    for (int kt = 0; kt < 2; ++kt)
        #pragma unroll
        for (int y = 0; y < 4; ++y)
            #pragma unroll
            for (int z = 0; z < 16; ++z) Y[kt][y][z] = 0.f;

    // stage step s: A 8 chunks (1KB), B 16 chunks; 6 chunks per wave
    auto stage = [&](int s) {
        int rb8 = s * 8;
        #pragma unroll
        for (int i = 0; i < 6; ++i) {
            int chunk = wave * 6 + i;                       // wave-uniform
            if (chunk < 8) {
                int h = chunk;
                async16(Vp + ((size_t)(rb8 + h) * NP + n0 + lane) * 8,
                        (char*)As + (h * 64) * 16);
            } else {
                int cB = chunk - 8, h = cB >> 1, half = cB & 1;
                async16(Up + ((size_t)(rb8 + h) * 256 + k0 + half * 64 + lane) * 8,
                        (char*)Bs + (h * 128 + half * 64) * 16);
            }
        }
    };

    stage(0);

    #pragma unroll
    for (int ad = 0; ad < 16; ++ad) {
        f32x16 m0, m1;
        #pragma unroll
        for (int z = 0; z < 16; ++z) { m0[z] = 0.f; m1[z] = 0.f; }

        #pragma unroll
        for (int half = 0; half < 2; ++half) {
            const int s = ad * 2 + half;
            __syncthreads();                  // staging of step s complete

            bf16x8 a[4], b0[4], b1[4];
            #pragma unroll
            for (int r = 0; r < 4; ++r) {
                int h = r * 2 + q2;
                a[r]  = *(const bf16x8*)&As[(h * 64  + wn * 32 + l31) * 8];
                b0[r] = *(const bf16x8*)&Bs[(h * 128 + wk * 64 + l31) * 8];
                b1[r] = *(const bf16x8*)&Bs[(h * 128 + wk * 64 + 32 + l31) * 8];
            }
            __syncthreads();                  // frags in regs; LDS reusable

            if (s < 31) stage(s + 1);         // async prefetch overlaps MFMA

            #pragma unroll
            for (int r = 0; r < 4; ++r) {
                m0 = __builtin_amdgcn_mfma_f32_32x32x16_bf16(a[r], b0[r], m0, 0, 0, 0);
                m1 = __builtin_amdgcn_mfma_f32_32x32x16_bf16(a[r], b1[r], m1, 0, 0, 0);
            }
        }

        const int a_i = ad >> 2, d_i = ad & 3;
        constexpr float A0[4] = {1.f, 1.f,  1.f,  0.f};
        constexpr float A1[4] = {0.f, 1.f, -1.f, -1.f};
        const float w00 = A0[a_i]*A0[d_i], w01 = A0[a_i]*A1[d_i];
        const float w10 = A1[a_i]*A0[d_i], w11 = A1[a_i]*A1[d_i];
        if (w00 != 0.f) { Y[0][0] += w00 * m0; Y[1][0] += w00 * m1; }
        if (w01 != 0.f) { Y[0][1] += w01 * m0; Y[1][1] += w01 * m1; }
        if (w10 != 0.f) { Y[0][2] += w10 * m0; Y[1][2] += w10 * m1; }
        if (w11 != 0.f) { Y[0][3] += w11 * m0; Y[1][3] += w11 * m1; }
    }

    // ---- epilogue: row = nb*2 + wn; q = (r&3)+8*(r>>2)+4*q2; k = k0+wk*64+kt*32+l31
    int row = nb * 2 + wn;                    // 0..991 = b*31 + p
    int b = row / 31, p = row - (row / 31) * 31;
    #pragma unroll
    for (int kt = 0; kt < 2; ++kt) {
        int k = k0 + wk * 64 + kt * 32 + l31;
        float bv = bias[k];
        float* op = out + (size_t)(b * 256 + k) * 62 * 62;
        #pragma unroll
        for (int r = 0; r < 16; ++r) {
            int q = (r & 3) + 8 * (r >> 2) + 4 * q2;
            if (q < 31) {
                float2 v0 = make_float2(Y[kt][0][r] + bv, Y[kt][1][r] + bv);
                float2 v1 = make_float2(Y[kt][2][r] + bv, Y[kt][3][r] + bv);
                *(float2*)(op + (2 * p + 0) * 62 + 2 * q) = v0;
                *(float2*)(op + (2 * p + 1) * 62 + 2 * q) = v1;
            }
        }
    }
}

// ---------------------------------------------------------------------------
extern "C" void kernel_launch(void* const* d_in, const int* in_sizes, int n_in,
                              void* d_out, int out_size, void* d_ws, size_t ws_size,
                              hipStream_t stream) {
    const float* x    = (const float*)d_in[0];
    const float* w    = (const float*)d_in[1];
    const float* bias = (const float*)d_in[2];
    float* out = (float*)d_out;

    unsigned short* Up = (unsigned short*)d_ws;        // 16*16*256*8 = 524288 bf16 = 1 MB
    unsigned short* Vp = Up + 524288;                  // 16*16*NP*8 bf16 = ~130 MB

    wino_wtrans<<<dim3(256),        dim3(128), 0, stream>>>(w, Up);
    wino_itrans<<<dim3(16, NROWS),  dim3(256), 0, stream>>>(x, Vp);
    wino_gemm  <<<dim3(992),        dim3(256), 0, stream>>>(Vp, Up, bias, out);
}